// Round 8
// baseline (532.999 us; speedup 1.0000x reference)
//
#include <hip/hip_runtime.h>

// Social-STGCN forward: 2x GCN(improved) + 3x GCLSTM(K=3 Cheb, H=C=0) + linear.
// N=50000 nodes, E=800000 edges, D=64.
//
// Exact simplifications (H=C=0 per cell): gh(g)=bh[g]; f gate dead; Cn=i*t.
// z2 = 2*lhat(z1) - X  =>  gate = X@(W0-W2) + z1@W1 + y@(2*W2), y = lhat(z1).
// W-fold done in pack_w; y gathered INSIDE the gate kernel (LDS -> MFMA A-frag),
// so z2 is never materialized. GCN2's gather and GCN1's gather+matmul fused too.
// Gathers read PRE-SCALED tables (P = dinv*x): pure row-sum inner loop.
// csr stored as ushort (N<65536). 16 dispatches total.

typedef _Float16 half8 __attribute__((ext_vector_type(8)));
typedef float f32x4 __attribute__((ext_vector_type(4)));

// ---------- CSR build ----------
__global__ void count_deg_kernel(const int* __restrict__ ei, int* __restrict__ deg, int E) {
  int e = blockIdx.x * blockDim.x + threadIdx.x;
  if (e < E) atomicAdd(&deg[ei[E + e]], 1);
}

__global__ void scan_block_sums(const int* __restrict__ deg, int* __restrict__ bsum, int n) {
  int tid = threadIdx.x;
  int i = blockIdx.x * 256 + tid;
  int v = (i < n) ? deg[i] : 0;
  for (int off = 32; off; off >>= 1) v += __shfl_down(v, off);
  __shared__ int ws[4];
  int lane = tid & 63, wid = tid >> 6;
  if (lane == 0) ws[wid] = v;
  __syncthreads();
  if (tid == 0) bsum[blockIdx.x] = ws[0] + ws[1] + ws[2] + ws[3];
}

__global__ void scan_final(const int* __restrict__ deg, const int* __restrict__ bsum, int nb,
                           int* __restrict__ rowptr, int* __restrict__ cursor,
                           float* __restrict__ dg, float* __restrict__ dc, int n) {
  __shared__ int tmp[256];
  __shared__ int ws[4];
  __shared__ int base_sh;
  int tid = threadIdx.x;
  int v0 = (tid < nb && tid < (int)blockIdx.x) ? bsum[tid] : 0;
  for (int off = 32; off; off >>= 1) v0 += __shfl_down(v0, off);
  if ((tid & 63) == 0) ws[tid >> 6] = v0;
  __syncthreads();
  if (tid == 0) base_sh = ws[0] + ws[1] + ws[2] + ws[3];
  int i = blockIdx.x * 256 + tid;
  int v = (i < n) ? deg[i] : 0;
  tmp[tid] = v;
  __syncthreads();
  for (int off = 1; off < 256; off <<= 1) {
    int t = (tid >= off) ? tmp[tid - off] : 0;
    __syncthreads();
    tmp[tid] += t;
    __syncthreads();
  }
  if (i < n) {
    int excl = tmp[tid] - v + base_sh;
    rowptr[i] = excl;
    cursor[i] = excl;
    dg[i] = rsqrtf((float)v + 2.f);
    dc[i] = (v > 0) ? rsqrtf((float)v) : 0.f;
  }
}

__global__ void fill_kernel(const int* __restrict__ ei, int* __restrict__ cursor,
                            unsigned short* __restrict__ csr, int E) {
  int e = blockIdx.x * blockDim.x + threadIdx.x;
  if (e < E) {
    int d = ei[E + e];
    int pos = atomicAdd(&cursor[d], 1);
    csr[pos] = (unsigned short)ei[e];
  }
}

// ---------- cast+scale x (N x 16 fp32) -> fp16 scaled by dinv_g ----------
__global__ void cast_x16_kernel(const float* __restrict__ x, const float* __restrict__ dg,
                                _Float16* __restrict__ x16s, int total) {
  int i = blockIdx.x * blockDim.x + threadIdx.x;
  if (i < total) x16s[i] = (_Float16)(dg[i >> 4] * x[i]);
}

// ---------- pack gate weights (W-FOLDED) -> fp16 MFMA B-frag layout ----------
// tau0 -> W0-W2 (X term), tau1 -> W1 (z1), tau2 -> 2*W2 (y term).
// Wpk[l][g][kc][nt][lane][j]; g in {i,c,o} = src gates {0,2,3}.
__global__ void pack_w_kernel(const float* __restrict__ wx0, const float* __restrict__ wx1,
                              const float* __restrict__ wx2, _Float16* __restrict__ Wpk) {
  int idx = blockIdx.x * 256 + threadIdx.x;
  if (idx >= 3 * 3 * 192 * 64) return;
  int l = idx / 36864;
  int r = idx % 36864;
  int g = r / 12288;
  int r2 = r % 12288;
  int k = r2 / 64;   // 0..191
  int n = r2 % 64;
  const float* wx = (l == 0) ? wx0 : (l == 1 ? wx1 : wx2);
  int gs = (g == 0) ? 0 : (g == 1 ? 2 : 3);
  int tau = k >> 6, kd = k & 63;
  size_t base = ((size_t)gs * 3) * 4096 + (size_t)kd * 64 + n;
  float v;
  if (tau == 0)      v = wx[base] - wx[base + 2 * 4096];
  else if (tau == 1) v = wx[base + 1 * 4096];
  else               v = 2.f * wx[base + 2 * 4096];
  int kc = k >> 5, klo = k & 31;
  int lane = ((klo >> 3) << 4) | (n & 15);
  int j = klo & 7;
  int nt = n >> 4;
  size_t dst = ((((size_t)l * 3 + g) * 6 + kc) * 4 + nt) * 512 + (size_t)lane * 8 + j;
  Wpk[dst] = (_Float16)v;
}

// ---------- pack w_gcn2 [64][64] -> B-frag layout [kc2][nt4][lane][8] ----------
__global__ void pack_w2_kernel(const float* __restrict__ W, _Float16* __restrict__ Wpk2) {
  int idx = blockIdx.x * 256 + threadIdx.x;
  if (idx >= 4096) return;
  int k = idx >> 6, n = idx & 63;
  float v = W[k * 64 + n];
  int kc = k >> 5, klo = k & 31;
  int lane = ((klo >> 3) << 4) | (n & 15);
  int j = klo & 7;
  int nt = n >> 4;
  Wpk2[(((size_t)kc * 4 + nt) * 64 + lane) * 8 + j] = (_Float16)v;
}

// ---------- GCN1 fused: agg16 = dg-agg(x16s), h1s = dg*relu(agg16 @ W1 + b1) ----------
// 8 nodes/block, 32 lanes/node (16 edge-slots x 2 half8-chunks).
__global__ __launch_bounds__(256) void gcn1_fused_kernel(
    const _Float16* __restrict__ X16s, const float* __restrict__ W1,
    const float* __restrict__ b1, const float* __restrict__ dg,
    _Float16* __restrict__ OUTs,
    const int* __restrict__ rowptr, const int* __restrict__ deg,
    const unsigned short* __restrict__ csr, int n) {
  __shared__ float w1s[16 * 64];
  int tid = threadIdx.x;
  for (int i = tid; i < 1024; i += 256) w1s[i] = W1[i];
  __syncthreads();
  int node = blockIdx.x * 8 + (tid >> 5);
  if (node >= n) return;
  int lane = tid & 63;
  int l32 = tid & 31;
  int eg = l32 >> 1, c8 = l32 & 1;
  int beg = rowptr[node], end = beg + deg[node];
  const half8* IN8 = (const half8*)X16s;
  float acc[8];
#pragma unroll
  for (int j = 0; j < 8; ++j) acc[j] = 0.f;
  for (int p = beg + eg; p < end; p += 16) {
    int s = csr[p];
    half8 v = IN8[(size_t)s * 2 + c8];
#pragma unroll
    for (int j = 0; j < 8; ++j) acc[j] += (float)v[j];
  }
#pragma unroll
  for (int j = 0; j < 8; ++j) {
    acc[j] += __shfl_xor(acc[j], 2);
    acc[j] += __shfl_xor(acc[j], 4);
    acc[j] += __shfl_xor(acc[j], 8);
    acc[j] += __shfl_xor(acc[j], 16);
  }
  float dt = dg[node];
  half8 self = IN8[(size_t)node * 2 + c8];
  float v8[8];
#pragma unroll
  for (int j = 0; j < 8; ++j) v8[j] = dt * acc[j] + 2.f * dt * (float)self[j];
  float agg[16];
  int base = lane & 32;
#pragma unroll
  for (int k = 0; k < 16; ++k) agg[k] = __shfl(v8[k & 7], base + (k >> 3));
  float h0 = b1[l32], h1 = b1[l32 + 32];
#pragma unroll
  for (int k = 0; k < 16; ++k) {
    h0 += agg[k] * w1s[k * 64 + l32];
    h1 += agg[k] * w1s[k * 64 + l32 + 32];
  }
  float dgn = dt;  // output scaled by dg for GCN2's gather
  OUTs[(size_t)node * 64 + l32]      = (_Float16)(dgn * fmaxf(h0, 0.f));
  OUTs[(size_t)node * 64 + l32 + 32] = (_Float16)(dgn * fmaxf(h1, 0.f));
}

// ---------- GCN2 fused: gather agg rows -> LDS, MFMA with W2, relu ----------
// 64 nodes/block: wave wid gathers its 16 nodes into LDS, then MFMA.
__global__ __launch_bounds__(256) void gcn2_fused_kernel(
    const _Float16* __restrict__ H1s, const _Float16* __restrict__ W2,
    const float* __restrict__ bias, const float* __restrict__ dg,
    const float* __restrict__ dc,
    _Float16* __restrict__ OUT, _Float16* __restrict__ OUTs,
    const int* __restrict__ rowptr, const int* __restrict__ deg,
    const unsigned short* __restrict__ csr, int n) {
  __shared__ _Float16 Ylds[64 * 80];   // 64 rows x 64 (+16 pad) halves
  int tid = threadIdx.x;
  int wid = tid >> 6, lane = tid & 63;
  int n0 = blockIdx.x * 64;
  {
    int eg = lane >> 3, c8 = lane & 7;
    const half8* IN8 = (const half8*)H1s;
    for (int t = 0; t < 16; ++t) {
      int node = n0 + wid * 16 + t;
      int nodec = min(node, n - 1);
      int beg = rowptr[nodec], end = beg + deg[nodec];
      float acc[8];
#pragma unroll
      for (int j = 0; j < 8; ++j) acc[j] = 0.f;
      for (int p = beg + eg; p < end; p += 8) {
        int s = csr[p];
        half8 v = IN8[(size_t)s * 8 + c8];
#pragma unroll
        for (int j = 0; j < 8; ++j) acc[j] += (float)v[j];
      }
#pragma unroll
      for (int j = 0; j < 8; ++j) {
        acc[j] += __shfl_xor(acc[j], 8);
        acc[j] += __shfl_xor(acc[j], 16);
        acc[j] += __shfl_xor(acc[j], 32);
      }
      if (eg == 0) {
        float dt = dg[nodec];
        half8 self = IN8[(size_t)nodec * 8 + c8];
        half8 r;
#pragma unroll
        for (int j = 0; j < 8; ++j) r[j] = (_Float16)(dt * acc[j] + 2.f * dt * (float)self[j]);
        *(half8*)&Ylds[(size_t)(wid * 16 + t) * 80 + c8 * 8] = r;
      }
    }
  }
  __syncthreads();
  int ksub = (lane >> 4) << 3;
  int dbase = lane & 15;
  const _Float16* Wlane = W2 + (size_t)lane * 8;
  f32x4 acc[4];
#pragma unroll
  for (int nt = 0; nt < 4; ++nt) {
    float b = bias[nt * 16 + dbase];
    acc[nt] = (f32x4){b, b, b, b};
  }
#pragma unroll
  for (int kc = 0; kc < 2; ++kc) {
    half8 a = *(const half8*)&Ylds[(size_t)(wid * 16 + dbase) * 80 + (kc << 5) + ksub];
#pragma unroll
    for (int nt = 0; nt < 4; ++nt) {
      half8 b = *(const half8*)(Wlane + (size_t)(kc * 4 + nt) * 512);
      acc[nt] = __builtin_amdgcn_mfma_f32_16x16x32_f16(a, b, acc[nt], 0, 0, 0);
    }
  }
  int mrow = n0 + wid * 16 + ((lane >> 4) << 2);
#pragma unroll
  for (int nt = 0; nt < 4; ++nt) {
    int d = nt * 16 + dbase;
#pragma unroll
    for (int r = 0; r < 4; ++r) {
      int node = mrow + r;
      if (node < n) {
        float h = fmaxf(acc[nt][r], 0.f);
        OUT[(size_t)node * 64 + d] = (_Float16)h;
        OUTs[(size_t)node * 64 + d] = (_Float16)(dc[node] * h);
      }
    }
  }
}

// ---------- z1 gather: one wave/node; writes z1 and dc*z1 ----------
__global__ void gather_z1_kernel(const int* __restrict__ rowptr, const int* __restrict__ deg,
                                 const unsigned short* __restrict__ csr,
                                 const float* __restrict__ dinv,
                                 const _Float16* __restrict__ Xs,
                                 _Float16* __restrict__ Z1, _Float16* __restrict__ Z1s, int n) {
  int node = blockIdx.x * (blockDim.x >> 6) + (threadIdx.x >> 6);
  if (node >= n) return;
  int lane = threadIdx.x & 63;
  int eg = lane >> 3, c8 = lane & 7;
  int beg = rowptr[node], end = beg + deg[node];
  const half8* IN8 = (const half8*)Xs;
  float acc[8];
#pragma unroll
  for (int j = 0; j < 8; ++j) acc[j] = 0.f;
  for (int p = beg + eg; p < end; p += 8) {
    int s = csr[p];
    half8 v = IN8[(size_t)s * 8 + c8];
#pragma unroll
    for (int j = 0; j < 8; ++j) acc[j] += (float)v[j];
  }
#pragma unroll
  for (int j = 0; j < 8; ++j) {
    acc[j] += __shfl_xor(acc[j], 8);
    acc[j] += __shfl_xor(acc[j], 16);
    acc[j] += __shfl_xor(acc[j], 32);
  }
  if (eg == 0) {
    float dt = dinv[node];
    size_t o8 = (size_t)node * 8 + c8;
    half8 r, rs;
#pragma unroll
    for (int j = 0; j < 8; ++j) {
      float z = -dt * acc[j];
      r[j] = (_Float16)z;
      rs[j] = (_Float16)(dt * z);
    }
    ((half8*)Z1)[o8] = r;
    ((half8*)Z1s)[o8] = rs;
  }
}

// ---------- fused gate: y-gather (LDS) + MFMA (X, z1, y) + LSTM combine ----------
// FINAL=0: writes H and dc*H.  FINAL=1: fuses out = relu(H) @ lin_w + lin_b.
template <int FINAL>
__global__ __launch_bounds__(256) void gate_fused_kernel(
    const _Float16* __restrict__ X, const _Float16* __restrict__ Z1,
    const _Float16* __restrict__ Z1s,
    const _Float16* __restrict__ Wl,  // packed (folded) [3][6][4][64][8]
    const float* __restrict__ bx, const float* __restrict__ bh, const float* __restrict__ bg,
    const float* __restrict__ wc, const float* __restrict__ dc,
    _Float16* __restrict__ H, _Float16* __restrict__ Hs,
    const float* __restrict__ lw, const float* __restrict__ lb,
    float* __restrict__ out,
    const int* __restrict__ rowptr, const int* __restrict__ deg,
    const unsigned short* __restrict__ csr, int n) {
  __shared__ _Float16 Ylds[64 * 80];
  int tid = threadIdx.x;
  int wid = tid >> 6, lane = tid & 63;
  int n0 = blockIdx.x * 64;
  // ---- gather phase: y = -dt * sum(z1s rows) for this wave's 16 nodes
  {
    int eg = lane >> 3, c8 = lane & 7;
    const half8* IN8 = (const half8*)Z1s;
    for (int t = 0; t < 16; ++t) {
      int node = n0 + wid * 16 + t;
      int nodec = min(node, n - 1);
      int beg = rowptr[nodec], end = beg + deg[nodec];
      float acc[8];
#pragma unroll
      for (int j = 0; j < 8; ++j) acc[j] = 0.f;
      for (int p = beg + eg; p < end; p += 8) {
        int s = csr[p];
        half8 v = IN8[(size_t)s * 8 + c8];
#pragma unroll
        for (int j = 0; j < 8; ++j) acc[j] += (float)v[j];
      }
#pragma unroll
      for (int j = 0; j < 8; ++j) {
        acc[j] += __shfl_xor(acc[j], 8);
        acc[j] += __shfl_xor(acc[j], 16);
        acc[j] += __shfl_xor(acc[j], 32);
      }
      if (eg == 0) {
        float dt = dc[nodec];
        half8 r;
#pragma unroll
        for (int j = 0; j < 8; ++j) r[j] = (_Float16)(-dt * acc[j]);
        *(half8*)&Ylds[(size_t)(wid * 16 + t) * 80 + c8 * 8] = r;
      }
    }
  }
  __syncthreads();
  // ---- MFMA phase
  int row = n0 + wid * 16 + (lane & 15);
  int rowc = min(row, n - 1);
  int ksub = (lane >> 4) << 3;
  const _Float16* Wlane = Wl + (size_t)lane * 8;
  int dbase = lane & 15;

  f32x4 acc[3][4];
#pragma unroll
  for (int g = 0; g < 3; ++g) {
    int gs = (g == 0) ? 0 : (g == 1 ? 2 : 3);
#pragma unroll
    for (int nt = 0; nt < 4; ++nt) {
      int d = nt * 16 + dbase;
      float b = bx[gs * 64 + d] + bh[gs * 64 + d] + bg[gs * 64 + d];
      acc[g][nt] = (f32x4){b, b, b, b};
    }
  }
#pragma unroll
  for (int kc = 0; kc < 6; ++kc) {
    half8 a;
    if (kc < 2)      a = *(const half8*)&X[(size_t)rowc * 64 + ((kc & 1) << 5) + ksub];
    else if (kc < 4) a = *(const half8*)&Z1[(size_t)rowc * 64 + ((kc & 1) << 5) + ksub];
    else             a = *(const half8*)&Ylds[(size_t)(wid * 16 + dbase) * 80 + ((kc & 1) << 5) + ksub];
#pragma unroll
    for (int g = 0; g < 3; ++g) {
#pragma unroll
      for (int nt = 0; nt < 4; ++nt) {
        half8 b = *(const half8*)(Wlane + (size_t)((g * 6 + kc) * 4 + nt) * 512);
        acc[g][nt] = __builtin_amdgcn_mfma_f32_16x16x32_f16(a, b, acc[g][nt], 0, 0, 0);
      }
    }
  }
  int mrow = n0 + wid * 16 + ((lane >> 4) << 2);
  float po[4][3];
  if (FINAL) {
#pragma unroll
    for (int r = 0; r < 4; ++r) { po[r][0] = 0.f; po[r][1] = 0.f; po[r][2] = 0.f; }
  }
#pragma unroll
  for (int nt = 0; nt < 4; ++nt) {
    int d = nt * 16 + dbase;
    float wcd = wc[128 + d];
#pragma unroll
    for (int r = 0; r < 4; ++r) {
      float ig = 1.f / (1.f + expf(-acc[0][nt][r]));
      float tt = tanhf(acc[1][nt][r]);
      float Cn = ig * tt;
      float og = 1.f / (1.f + expf(-(acc[2][nt][r] + wcd * Cn)));
      float h = og * tanhf(Cn);
      if (FINAL) {
        float rl = fmaxf(h, 0.f);
        po[r][0] += rl * lw[d * 3 + 0];
        po[r][1] += rl * lw[d * 3 + 1];
        po[r][2] += rl * lw[d * 3 + 2];
      } else {
        int node = mrow + r;
        if (node < n) {
          H[(size_t)node * 64 + d] = (_Float16)h;
          Hs[(size_t)node * 64 + d] = (_Float16)(dc[node] * h);
        }
      }
    }
  }
  if (FINAL) {
#pragma unroll
    for (int m = 1; m < 16; m <<= 1) {
#pragma unroll
      for (int r = 0; r < 4; ++r) {
        po[r][0] += __shfl_xor(po[r][0], m);
        po[r][1] += __shfl_xor(po[r][1], m);
        po[r][2] += __shfl_xor(po[r][2], m);
      }
    }
    if (dbase == 0) {
#pragma unroll
      for (int r = 0; r < 4; ++r) {
        int node = mrow + r;
        if (node < n) {
          out[(size_t)node * 3 + 0] = po[r][0] + lb[0];
          out[(size_t)node * 3 + 1] = po[r][1] + lb[1];
          out[(size_t)node * 3 + 2] = po[r][2] + lb[2];
        }
      }
    }
  }
}

extern "C" void kernel_launch(void* const* d_in, const int* in_sizes, int n_in,
                              void* d_out, int out_size, void* d_ws, size_t ws_size,
                              hipStream_t stream) {
  const float* x      = (const float*)d_in[0];
  const int*   ei     = (const int*)d_in[1];
  const float* w_gcn1 = (const float*)d_in[2];
  const float* b_gcn1 = (const float*)d_in[3];
  const float* w_gcn2 = (const float*)d_in[4];
  const float* b_gcn2 = (const float*)d_in[5];
  const float* wx[3]  = {(const float*)d_in[6],  (const float*)d_in[12], (const float*)d_in[18]};
  const float* bx[3]  = {(const float*)d_in[7],  (const float*)d_in[13], (const float*)d_in[19]};
  const float* bh[3]  = {(const float*)d_in[9],  (const float*)d_in[15], (const float*)d_in[21]};
  const float* wc[3]  = {(const float*)d_in[10], (const float*)d_in[16], (const float*)d_in[22]};
  const float* bg[3]  = {(const float*)d_in[11], (const float*)d_in[17], (const float*)d_in[23]};
  const float* lin_w  = (const float*)d_in[24];
  const float* lin_b  = (const float*)d_in[25];
  float* out = (float*)d_out;

  int N = in_sizes[0] / 16;
  int E = in_sizes[1] / 2;
  int nsb = (N + 255) / 256;

  char* ws = (char*)d_ws;
  size_t off = 0;
  auto alloc = [&](size_t bytes) {
    void* p = ws + off;
    off = (off + bytes + 255) & ~(size_t)255;
    return p;
  };
  int* deg        = (int*)alloc((size_t)N * 4);
  int* rowptr     = (int*)alloc((size_t)N * 4);
  int* cursor     = (int*)alloc((size_t)N * 4);
  int* bsum       = (int*)alloc((size_t)nsb * 4);
  unsigned short* csr = (unsigned short*)alloc((size_t)E * 2);
  float* dinv_g   = (float*)alloc((size_t)N * 4);
  float* dinv_c   = (float*)alloc((size_t)N * 4);
  _Float16* Wpk   = (_Float16*)alloc((size_t)3 * 36864 * 2);
  _Float16* Wpk2  = (_Float16*)alloc((size_t)4096 * 2);
  _Float16* x16s  = (_Float16*)alloc((size_t)N * 16 * 2);
  _Float16* bufA  = (_Float16*)alloc((size_t)N * 64 * 2);   // X (unscaled)
  _Float16* bufAs = (_Float16*)alloc((size_t)N * 64 * 2);   // dc*X
  _Float16* bufB  = (_Float16*)alloc((size_t)N * 64 * 2);   // h1s / z1
  _Float16* bufBs = (_Float16*)alloc((size_t)N * 64 * 2);   // dc*z1
  (void)ws_size; (void)n_in; (void)out_size;

  const int tb = 256;
  hipMemsetAsync(deg, 0, (size_t)N * 4, stream);
  count_deg_kernel<<<(E + tb - 1) / tb, tb, 0, stream>>>(ei, deg, E);
  scan_block_sums<<<nsb, 256, 0, stream>>>(deg, bsum, N);
  scan_final<<<nsb, 256, 0, stream>>>(deg, bsum, nsb, rowptr, cursor, dinv_g, dinv_c, N);
  fill_kernel<<<(E + tb - 1) / tb, tb, 0, stream>>>(ei, cursor, csr, E);
  pack_w_kernel<<<(110592 + 255) / 256, 256, 0, stream>>>(wx[0], wx[1], wx[2], Wpk);
  pack_w2_kernel<<<16, 256, 0, stream>>>(w_gcn2, Wpk2);
  cast_x16_kernel<<<(N * 16 + 255) / 256, 256, 0, stream>>>(x, dinv_g, x16s, N * 16);

  int nb64 = (N + 63) / 64;
  int nbw  = (N + 3) / 4;
  int nb8  = (N + 7) / 8;

  // GCN1 fused: h1s = dg*relu(agg16 @ W1 + b1)      -> bufB
  gcn1_fused_kernel<<<nb8, 256, 0, stream>>>(x16s, w_gcn1, b_gcn1, dinv_g, bufB,
                                             rowptr, deg, csr, N);
  // GCN2 fused: h2 = relu(agg(h1s) @ W2 + b2)       -> bufA, bufAs
  gcn2_fused_kernel<<<nb64, 256, 0, stream>>>(bufB, Wpk2, b_gcn2, dinv_g, dinv_c,
                                              bufA, bufAs, rowptr, deg, csr, N);

  // 3x GCLSTM: z1 gather + fused gate (y gathered in-kernel)
  for (int l = 0; l < 3; ++l) {
    gather_z1_kernel<<<nbw, 256, 0, stream>>>(rowptr, deg, csr, dinv_c, bufAs, bufB, bufBs, N);
    if (l < 2) {
      gate_fused_kernel<0><<<nb64, 256, 0, stream>>>(bufA, bufB, bufBs, Wpk + (size_t)l * 36864,
                                                     bx[l], bh[l], bg[l], wc[l], dinv_c,
                                                     bufA, bufAs, nullptr, nullptr, nullptr,
                                                     rowptr, deg, csr, N);
    } else {
      gate_fused_kernel<1><<<nb64, 256, 0, stream>>>(bufA, bufB, bufBs, Wpk + (size_t)l * 36864,
                                                     bx[l], bh[l], bg[l], wc[l], dinv_c,
                                                     nullptr, nullptr, lin_w, lin_b, out,
                                                     rowptr, deg, csr, N);
    }
  }
}

// Round 9
// 384.780 us; speedup vs baseline: 1.3852x; 1.3852x over previous
//
#include <hip/hip_runtime.h>

// Social-STGCN forward: 2x GCN(improved) + 3x GCLSTM(K=3 Cheb, H=C=0) + linear.
// N=50000 nodes, E=800000 edges, D=64.
//
// Exact simplifications (H=C=0 per cell): gh(g)=bh[g]; f gate dead; Cn=i*t.
// z2 = 2*lhat(z1) - X  =>  gate = X@(W0-W2) + z1@W1 + y@(2*W2), y = lhat(z1)
// (fold in pack_w; y gathered by a STANDALONE wave-per-node gather — in-kernel
// fusion of the gather regressed 2.5x in r8: serial 16-node loop, 18% occ).
// Gathers read PRE-SCALED tables (P = dinv*x): pure row-sum inner loop.
// CSR build is XCD-RANGE-PARTITIONED (blockIdx%8 == dst range): deg/cursor/csr
// slices stay in one XCD's L2 -> kills cross-XCD line ping-pong (fill wrote
// 53MB HBM for a 1.6MB array). csr stored as ushort (N<65536).

typedef _Float16 half8 __attribute__((ext_vector_type(8)));
typedef float f32x4 __attribute__((ext_vector_type(4)));

// ---------- CSR build (XCD-range partitioned) ----------
__global__ void count_deg_x_kernel(const int* __restrict__ ei, int* __restrict__ deg,
                                   int E, int chunk) {
  int range = blockIdx.x & 7;
  int lo = range * chunk, hi = lo + chunk;
  int stride = (gridDim.x >> 3) * blockDim.x;
  for (int e = (blockIdx.x >> 3) * blockDim.x + threadIdx.x; e < E; e += stride) {
    int d = ei[E + e];
    if (d >= lo && d < hi) atomicAdd(&deg[d], 1);
  }
}

__global__ void fill_x_kernel(const int* __restrict__ ei, int* __restrict__ cursor,
                              unsigned short* __restrict__ csr, int E, int chunk) {
  int range = blockIdx.x & 7;
  int lo = range * chunk, hi = lo + chunk;
  int stride = (gridDim.x >> 3) * blockDim.x;
  for (int e = (blockIdx.x >> 3) * blockDim.x + threadIdx.x; e < E; e += stride) {
    int d = ei[E + e];
    if (d >= lo && d < hi) {
      int pos = atomicAdd(&cursor[d], 1);
      csr[pos] = (unsigned short)ei[e];
    }
  }
}

__global__ void scan_block_sums(const int* __restrict__ deg, int* __restrict__ bsum, int n) {
  int tid = threadIdx.x;
  int i = blockIdx.x * 256 + tid;
  int v = (i < n) ? deg[i] : 0;
  for (int off = 32; off; off >>= 1) v += __shfl_down(v, off);
  __shared__ int ws[4];
  int lane = tid & 63, wid = tid >> 6;
  if (lane == 0) ws[wid] = v;
  __syncthreads();
  if (tid == 0) bsum[blockIdx.x] = ws[0] + ws[1] + ws[2] + ws[3];
}

__global__ void scan_final(const int* __restrict__ deg, const int* __restrict__ bsum, int nb,
                           int* __restrict__ rowptr, int* __restrict__ cursor,
                           float* __restrict__ dg, float* __restrict__ dc, int n) {
  __shared__ int tmp[256];
  __shared__ int ws[4];
  __shared__ int base_sh;
  int tid = threadIdx.x;
  int v0 = (tid < nb && tid < (int)blockIdx.x) ? bsum[tid] : 0;
  for (int off = 32; off; off >>= 1) v0 += __shfl_down(v0, off);
  if ((tid & 63) == 0) ws[tid >> 6] = v0;
  __syncthreads();
  if (tid == 0) base_sh = ws[0] + ws[1] + ws[2] + ws[3];
  int i = blockIdx.x * 256 + tid;
  int v = (i < n) ? deg[i] : 0;
  tmp[tid] = v;
  __syncthreads();
  for (int off = 1; off < 256; off <<= 1) {
    int t = (tid >= off) ? tmp[tid - off] : 0;
    __syncthreads();
    tmp[tid] += t;
    __syncthreads();
  }
  if (i < n) {
    int excl = tmp[tid] - v + base_sh;
    rowptr[i] = excl;
    cursor[i] = excl;
    dg[i] = rsqrtf((float)v + 2.f);
    dc[i] = (v > 0) ? rsqrtf((float)v) : 0.f;
  }
}

// ---------- cast+scale x (N x 16 fp32) -> fp16 scaled by dinv_g ----------
__global__ void cast_x16_kernel(const float* __restrict__ x, const float* __restrict__ dg,
                                _Float16* __restrict__ x16s, int total) {
  int i = blockIdx.x * blockDim.x + threadIdx.x;
  if (i < total) x16s[i] = (_Float16)(dg[i >> 4] * x[i]);
}

// ---------- pack gate weights (W-FOLDED) -> fp16 MFMA B-frag layout ----------
// tau0 -> W0-W2 (X term), tau1 -> W1 (z1), tau2 -> 2*W2 (y term).
__global__ void pack_w_kernel(const float* __restrict__ wx0, const float* __restrict__ wx1,
                              const float* __restrict__ wx2, _Float16* __restrict__ Wpk) {
  int idx = blockIdx.x * 256 + threadIdx.x;
  if (idx >= 3 * 3 * 192 * 64) return;
  int l = idx / 36864;
  int r = idx % 36864;
  int g = r / 12288;
  int r2 = r % 12288;
  int k = r2 / 64;   // 0..191
  int n = r2 % 64;
  const float* wx = (l == 0) ? wx0 : (l == 1 ? wx1 : wx2);
  int gs = (g == 0) ? 0 : (g == 1 ? 2 : 3);
  int tau = k >> 6, kd = k & 63;
  size_t base = ((size_t)gs * 3) * 4096 + (size_t)kd * 64 + n;
  float v;
  if (tau == 0)      v = wx[base] - wx[base + 2 * 4096];
  else if (tau == 1) v = wx[base + 1 * 4096];
  else               v = 2.f * wx[base + 2 * 4096];
  int kc = k >> 5, klo = k & 31;
  int lane = ((klo >> 3) << 4) | (n & 15);
  int j = klo & 7;
  int nt = n >> 4;
  size_t dst = ((((size_t)l * 3 + g) * 6 + kc) * 4 + nt) * 512 + (size_t)lane * 8 + j;
  Wpk[dst] = (_Float16)v;
}

// ---------- pack w_gcn2 [64][64] -> B-frag layout [kc2][nt4][lane][8] ----------
__global__ void pack_w2_kernel(const float* __restrict__ W, _Float16* __restrict__ Wpk2) {
  int idx = blockIdx.x * 256 + threadIdx.x;
  if (idx >= 4096) return;
  int k = idx >> 6, n = idx & 63;
  float v = W[k * 64 + n];
  int kc = k >> 5, klo = k & 31;
  int lane = ((klo >> 3) << 4) | (n & 15);
  int j = klo & 7;
  int nt = n >> 4;
  Wpk2[(((size_t)kc * 4 + nt) * 64 + lane) * 8 + j] = (_Float16)v;
}

// ---------- GCN1 fused: agg16 (parallel 32-lane gather) + 16->64 matmul ----------
__global__ __launch_bounds__(256) void gcn1_fused_kernel(
    const _Float16* __restrict__ X16s, const float* __restrict__ W1,
    const float* __restrict__ b1, const float* __restrict__ dg,
    _Float16* __restrict__ OUTs,
    const int* __restrict__ rowptr, const int* __restrict__ deg,
    const unsigned short* __restrict__ csr, int n) {
  __shared__ float w1s[16 * 64];
  int tid = threadIdx.x;
  for (int i = tid; i < 1024; i += 256) w1s[i] = W1[i];
  __syncthreads();
  int node = blockIdx.x * 8 + (tid >> 5);
  if (node >= n) return;
  int lane = tid & 63;
  int l32 = tid & 31;
  int eg = l32 >> 1, c8 = l32 & 1;
  int beg = rowptr[node], end = beg + deg[node];
  const half8* IN8 = (const half8*)X16s;
  float acc[8];
#pragma unroll
  for (int j = 0; j < 8; ++j) acc[j] = 0.f;
  for (int p = beg + eg; p < end; p += 16) {
    int s = csr[p];
    half8 v = IN8[(size_t)s * 2 + c8];
#pragma unroll
    for (int j = 0; j < 8; ++j) acc[j] += (float)v[j];
  }
#pragma unroll
  for (int j = 0; j < 8; ++j) {
    acc[j] += __shfl_xor(acc[j], 2);
    acc[j] += __shfl_xor(acc[j], 4);
    acc[j] += __shfl_xor(acc[j], 8);
    acc[j] += __shfl_xor(acc[j], 16);
  }
  float dt = dg[node];
  half8 self = IN8[(size_t)node * 2 + c8];
  float v8[8];
#pragma unroll
  for (int j = 0; j < 8; ++j) v8[j] = dt * acc[j] + 2.f * dt * (float)self[j];
  float agg[16];
  int base = lane & 32;
#pragma unroll
  for (int k = 0; k < 16; ++k) agg[k] = __shfl(v8[k & 7], base + (k >> 3));
  float h0 = b1[l32], h1 = b1[l32 + 32];
#pragma unroll
  for (int k = 0; k < 16; ++k) {
    h0 += agg[k] * w1s[k * 64 + l32];
    h1 += agg[k] * w1s[k * 64 + l32 + 32];
  }
  OUTs[(size_t)node * 64 + l32]      = (_Float16)(dt * fmaxf(h0, 0.f));
  OUTs[(size_t)node * 64 + l32 + 32] = (_Float16)(dt * fmaxf(h1, 0.f));
}

// ---------- gather (64-dim): one wave/node, 8 edge-slots x 8 half8-lanes ----------
// MODE 0: GCN  -> OUT = dt*acc + 2*dt*INs[node]
// MODE 1: z1   -> OUT = -dt*acc;  OUTs = -dt^2*acc
// MODE 3: y    -> OUT = -dt*acc
template <int MODE>
__global__ void gather_kernel(const int* __restrict__ rowptr, const int* __restrict__ deg,
                              const unsigned short* __restrict__ csr,
                              const float* __restrict__ dinv,
                              const _Float16* __restrict__ INs,
                              _Float16* __restrict__ OUT, _Float16* __restrict__ OUTs, int n) {
  int node = blockIdx.x * (blockDim.x >> 6) + (threadIdx.x >> 6);
  if (node >= n) return;
  int lane = threadIdx.x & 63;
  int eg = lane >> 3, c8 = lane & 7;
  int beg = rowptr[node], end = beg + deg[node];
  const half8* IN8 = (const half8*)INs;
  float acc[8];
#pragma unroll
  for (int j = 0; j < 8; ++j) acc[j] = 0.f;
  for (int p = beg + eg; p < end; p += 8) {
    int s = csr[p];
    half8 v = IN8[(size_t)s * 8 + c8];
#pragma unroll
    for (int j = 0; j < 8; ++j) acc[j] += (float)v[j];
  }
#pragma unroll
  for (int j = 0; j < 8; ++j) {
    acc[j] += __shfl_xor(acc[j], 8);
    acc[j] += __shfl_xor(acc[j], 16);
    acc[j] += __shfl_xor(acc[j], 32);
  }
  if (eg == 0) {
    float dt = dinv[node];
    size_t o8 = (size_t)node * 8 + c8;
    half8 r;
    if (MODE == 0) {
      half8 self = IN8[o8];
#pragma unroll
      for (int j = 0; j < 8; ++j) r[j] = (_Float16)(dt * acc[j] + 2.f * dt * (float)self[j]);
      ((half8*)OUT)[o8] = r;
    } else if (MODE == 1) {
      half8 rs;
#pragma unroll
      for (int j = 0; j < 8; ++j) {
        float z = -dt * acc[j];
        r[j] = (_Float16)z;
        rs[j] = (_Float16)(dt * z);
      }
      ((half8*)OUT)[o8] = r;
      ((half8*)OUTs)[o8] = rs;
    } else {
#pragma unroll
      for (int j = 0; j < 8; ++j) r[j] = (_Float16)(-dt * acc[j]);
      ((half8*)OUT)[o8] = r;
    }
  }
}

// ---------- GCN2 on MFMA: h2 = relu(A @ W2 + b); writes h2 and dc*h2 ----------
__global__ __launch_bounds__(256) void gcn2_mfma_kernel(
    const _Float16* __restrict__ A, const _Float16* __restrict__ W2,
    const float* __restrict__ bias, const float* __restrict__ dc,
    _Float16* __restrict__ OUT, _Float16* __restrict__ OUTs, int n) {
  int tid = threadIdx.x;
  int wid = tid >> 6, lane = tid & 63;
  int n0 = blockIdx.x * 64;
  int row = n0 + wid * 16 + (lane & 15);
  int rowc = min(row, n - 1);
  int ksub = (lane >> 4) << 3;
  int dbase = lane & 15;
  const _Float16* Wlane = W2 + (size_t)lane * 8;
  f32x4 acc[4];
#pragma unroll
  for (int nt = 0; nt < 4; ++nt) {
    float b = bias[nt * 16 + dbase];
    acc[nt] = (f32x4){b, b, b, b};
  }
#pragma unroll
  for (int kc = 0; kc < 2; ++kc) {
    half8 a = *(const half8*)&A[(size_t)rowc * 64 + (kc << 5) + ksub];
#pragma unroll
    for (int nt = 0; nt < 4; ++nt) {
      half8 b = *(const half8*)(Wlane + (size_t)(kc * 4 + nt) * 512);
      acc[nt] = __builtin_amdgcn_mfma_f32_16x16x32_f16(a, b, acc[nt], 0, 0, 0);
    }
  }
  int mrow = n0 + wid * 16 + ((lane >> 4) << 2);
#pragma unroll
  for (int nt = 0; nt < 4; ++nt) {
    int d = nt * 16 + dbase;
#pragma unroll
    for (int r = 0; r < 4; ++r) {
      int node = mrow + r;
      if (node < n) {
        float h = fmaxf(acc[nt][r], 0.f);
        OUT[(size_t)node * 64 + d] = (_Float16)h;
        OUTs[(size_t)node * 64 + d] = (_Float16)(dc[node] * h);
      }
    }
  }
}

// ---------- MFMA gate kernel: A-frags from X, Z1, Y (folded weights) ----------
// FINAL=0: writes H and dc*H.  FINAL=1: fuses out = relu(H) @ lin_w + lin_b.
template <int FINAL>
__global__ __launch_bounds__(256) void gate_mfma_kernel(
    const _Float16* __restrict__ X, const _Float16* __restrict__ Z1,
    const _Float16* __restrict__ Y,
    const _Float16* __restrict__ Wl,  // packed folded [3][6][4][64][8]
    const float* __restrict__ bx, const float* __restrict__ bh, const float* __restrict__ bg,
    const float* __restrict__ wc, const float* __restrict__ dc,
    _Float16* __restrict__ H, _Float16* __restrict__ Hs,
    const float* __restrict__ lw, const float* __restrict__ lb,
    float* __restrict__ out, int n) {
  int tid = threadIdx.x;
  int wid = tid >> 6, lane = tid & 63;
  int n0 = blockIdx.x * 64;
  int row = n0 + wid * 16 + (lane & 15);
  int rowc = min(row, n - 1);
  int ksub = (lane >> 4) << 3;
  const _Float16* Wlane = Wl + (size_t)lane * 8;
  int dbase = lane & 15;

  f32x4 acc[3][4];
#pragma unroll
  for (int g = 0; g < 3; ++g) {
    int gs = (g == 0) ? 0 : (g == 1 ? 2 : 3);
#pragma unroll
    for (int nt = 0; nt < 4; ++nt) {
      int d = nt * 16 + dbase;
      float b = bx[gs * 64 + d] + bh[gs * 64 + d] + bg[gs * 64 + d];
      acc[g][nt] = (f32x4){b, b, b, b};
    }
  }
  const _Float16* T[3] = {X, Z1, Y};
#pragma unroll
  for (int kc = 0; kc < 6; ++kc) {
    const _Float16* t = T[kc >> 1];
    half8 a = *(const half8*)&t[(size_t)rowc * 64 + ((kc & 1) << 5) + ksub];
#pragma unroll
    for (int g = 0; g < 3; ++g) {
#pragma unroll
      for (int nt = 0; nt < 4; ++nt) {
        half8 b = *(const half8*)(Wlane + (size_t)((g * 6 + kc) * 4 + nt) * 512);
        acc[g][nt] = __builtin_amdgcn_mfma_f32_16x16x32_f16(a, b, acc[g][nt], 0, 0, 0);
      }
    }
  }
  int mrow = n0 + wid * 16 + ((lane >> 4) << 2);
  float po[4][3];
  if (FINAL) {
#pragma unroll
    for (int r = 0; r < 4; ++r) { po[r][0] = 0.f; po[r][1] = 0.f; po[r][2] = 0.f; }
  }
#pragma unroll
  for (int nt = 0; nt < 4; ++nt) {
    int d = nt * 16 + dbase;
    float wcd = wc[128 + d];
#pragma unroll
    for (int r = 0; r < 4; ++r) {
      float ig = 1.f / (1.f + expf(-acc[0][nt][r]));
      float tt = tanhf(acc[1][nt][r]);
      float Cn = ig * tt;
      float og = 1.f / (1.f + expf(-(acc[2][nt][r] + wcd * Cn)));
      float h = og * tanhf(Cn);
      if (FINAL) {
        float rl = fmaxf(h, 0.f);
        po[r][0] += rl * lw[d * 3 + 0];
        po[r][1] += rl * lw[d * 3 + 1];
        po[r][2] += rl * lw[d * 3 + 2];
      } else {
        int node = mrow + r;
        if (node < n) {
          H[(size_t)node * 64 + d] = (_Float16)h;
          Hs[(size_t)node * 64 + d] = (_Float16)(dc[node] * h);
        }
      }
    }
  }
  if (FINAL) {
#pragma unroll
    for (int m = 1; m < 16; m <<= 1) {
#pragma unroll
      for (int r = 0; r < 4; ++r) {
        po[r][0] += __shfl_xor(po[r][0], m);
        po[r][1] += __shfl_xor(po[r][1], m);
        po[r][2] += __shfl_xor(po[r][2], m);
      }
    }
    if (dbase == 0) {
#pragma unroll
      for (int r = 0; r < 4; ++r) {
        int node = mrow + r;
        if (node < n) {
          out[(size_t)node * 3 + 0] = po[r][0] + lb[0];
          out[(size_t)node * 3 + 1] = po[r][1] + lb[1];
          out[(size_t)node * 3 + 2] = po[r][2] + lb[2];
        }
      }
    }
  }
}

extern "C" void kernel_launch(void* const* d_in, const int* in_sizes, int n_in,
                              void* d_out, int out_size, void* d_ws, size_t ws_size,
                              hipStream_t stream) {
  const float* x      = (const float*)d_in[0];
  const int*   ei     = (const int*)d_in[1];
  const float* w_gcn1 = (const float*)d_in[2];
  const float* b_gcn1 = (const float*)d_in[3];
  const float* w_gcn2 = (const float*)d_in[4];
  const float* b_gcn2 = (const float*)d_in[5];
  const float* wx[3]  = {(const float*)d_in[6],  (const float*)d_in[12], (const float*)d_in[18]};
  const float* bx[3]  = {(const float*)d_in[7],  (const float*)d_in[13], (const float*)d_in[19]};
  const float* bh[3]  = {(const float*)d_in[9],  (const float*)d_in[15], (const float*)d_in[21]};
  const float* wc[3]  = {(const float*)d_in[10], (const float*)d_in[16], (const float*)d_in[22]};
  const float* bg[3]  = {(const float*)d_in[11], (const float*)d_in[17], (const float*)d_in[23]};
  const float* lin_w  = (const float*)d_in[24];
  const float* lin_b  = (const float*)d_in[25];
  float* out = (float*)d_out;

  int N = in_sizes[0] / 16;
  int E = in_sizes[1] / 2;
  int nsb = (N + 255) / 256;
  int chunk = (N + 7) / 8;

  char* ws = (char*)d_ws;
  size_t off = 0;
  auto alloc = [&](size_t bytes) {
    void* p = ws + off;
    off = (off + bytes + 255) & ~(size_t)255;
    return p;
  };
  int* deg        = (int*)alloc((size_t)N * 4);
  int* rowptr     = (int*)alloc((size_t)N * 4);
  int* cursor     = (int*)alloc((size_t)N * 4);
  int* bsum       = (int*)alloc((size_t)nsb * 4);
  unsigned short* csr = (unsigned short*)alloc((size_t)E * 2);
  float* dinv_g   = (float*)alloc((size_t)N * 4);
  float* dinv_c   = (float*)alloc((size_t)N * 4);
  _Float16* Wpk   = (_Float16*)alloc((size_t)3 * 36864 * 2);
  _Float16* Wpk2  = (_Float16*)alloc((size_t)4096 * 2);
  _Float16* x16s  = (_Float16*)alloc((size_t)N * 16 * 2);
  _Float16* bufA  = (_Float16*)alloc((size_t)N * 64 * 2);   // X (unscaled)
  _Float16* bufAs = (_Float16*)alloc((size_t)N * 64 * 2);   // dc*X
  _Float16* bufB  = (_Float16*)alloc((size_t)N * 64 * 2);   // h1s / z1
  _Float16* bufBs = (_Float16*)alloc((size_t)N * 64 * 2);   // dc*z1
  _Float16* bufC  = (_Float16*)alloc((size_t)N * 64 * 2);   // gcn2-agg / y
  (void)ws_size; (void)n_in; (void)out_size;

  hipMemsetAsync(deg, 0, (size_t)N * 4, stream);
  count_deg_x_kernel<<<4096, 256, 0, stream>>>(ei, deg, E, chunk);
  scan_block_sums<<<nsb, 256, 0, stream>>>(deg, bsum, N);
  scan_final<<<nsb, 256, 0, stream>>>(deg, bsum, nsb, rowptr, cursor, dinv_g, dinv_c, N);
  fill_x_kernel<<<4096, 256, 0, stream>>>(ei, cursor, csr, E, chunk);
  pack_w_kernel<<<(110592 + 255) / 256, 256, 0, stream>>>(wx[0], wx[1], wx[2], Wpk);
  pack_w2_kernel<<<16, 256, 0, stream>>>(w_gcn2, Wpk2);
  cast_x16_kernel<<<(N * 16 + 255) / 256, 256, 0, stream>>>(x, dinv_g, x16s, N * 16);

  int nb64 = (N + 63) / 64;
  int nbw  = (N + 3) / 4;
  int nb8  = (N + 7) / 8;

  // GCN1 fused: h1s = dg*relu(agg16 @ W1 + b1)      -> bufB
  gcn1_fused_kernel<<<nb8, 256, 0, stream>>>(x16s, w_gcn1, b_gcn1, dinv_g, bufB,
                                             rowptr, deg, csr, N);
  // GCN2: aggC = agg(h1s); h2 = relu(aggC @ W2 + b2) -> bufA, bufAs
  gather_kernel<0><<<nbw, 256, 0, stream>>>(rowptr, deg, csr, dinv_g, bufB, bufC, nullptr, N);
  gcn2_mfma_kernel<<<nb64, 256, 0, stream>>>(bufC, Wpk2, b_gcn2, dinv_c, bufA, bufAs, N);

  // 3x GCLSTM: z1 gather, y gather, gate (folded weights)
  for (int l = 0; l < 3; ++l) {
    gather_kernel<1><<<nbw, 256, 0, stream>>>(rowptr, deg, csr, dinv_c, bufAs, bufB, bufBs, N);
    gather_kernel<3><<<nbw, 256, 0, stream>>>(rowptr, deg, csr, dinv_c, bufBs, bufC, nullptr, N);
    if (l < 2) {
      gate_mfma_kernel<0><<<nb64, 256, 0, stream>>>(bufA, bufB, bufC, Wpk + (size_t)l * 36864,
                                                    bx[l], bh[l], bg[l], wc[l], dinv_c,
                                                    bufA, bufAs, nullptr, nullptr, nullptr, N);
    } else {
      gate_mfma_kernel<1><<<nb64, 256, 0, stream>>>(bufA, bufB, bufC, Wpk + (size_t)l * 36864,
                                                    bx[l], bh[l], bg[l], wc[l], dinv_c,
                                                    nullptr, nullptr, lin_w, lin_b, out, N);
    }
  }
}

// Round 10
// 357.831 us; speedup vs baseline: 1.4895x; 1.0753x over previous
//
#include <hip/hip_runtime.h>

// Social-STGCN forward: 2x GCN(improved) + 3x GCLSTM(K=3 Cheb, H=C=0) + linear.
// N=50000 nodes, E=800000 edges, D=64.
//
// Exact simplifications (H=C=0 per cell): gh(g)=bh[g]; f gate dead; Cn=i*t.
// z2 = 2*lhat(z1) - X  =>  gate = X@(W0-W2) + z1@W1 + y@(2*W2), y = lhat(z1)
// (fold in pack_w; standalone wave-per-node gathers — in-kernel fusion regressed).
// Gathers read PRE-SCALED tables; edge loop UNROLLED x2 (16 rows in flight).
// z1 stored only as z1s = dc*z1; gate reconstructs z1 = z1s*sqrt(deg) per row
// (exact: deg-0 rows have z1s = z1 = 0).
// CSR build XCD-range-partitioned. csr as ushort (N<65536). 16 dispatches.

typedef _Float16 half8 __attribute__((ext_vector_type(8)));
typedef float f32x4 __attribute__((ext_vector_type(4)));

// ---------- CSR build (XCD-range partitioned) ----------
__global__ void count_deg_x_kernel(const int* __restrict__ ei, int* __restrict__ deg,
                                   int E, int chunk) {
  int range = blockIdx.x & 7;
  int lo = range * chunk, hi = lo + chunk;
  int stride = (gridDim.x >> 3) * blockDim.x;
  for (int e = (blockIdx.x >> 3) * blockDim.x + threadIdx.x; e < E; e += stride) {
    int d = ei[E + e];
    if (d >= lo && d < hi) atomicAdd(&deg[d], 1);
  }
}

__global__ void fill_x_kernel(const int* __restrict__ ei, int* __restrict__ cursor,
                              unsigned short* __restrict__ csr, int E, int chunk) {
  int range = blockIdx.x & 7;
  int lo = range * chunk, hi = lo + chunk;
  int stride = (gridDim.x >> 3) * blockDim.x;
  for (int e = (blockIdx.x >> 3) * blockDim.x + threadIdx.x; e < E; e += stride) {
    int d = ei[E + e];
    if (d >= lo && d < hi) {
      int pos = atomicAdd(&cursor[d], 1);
      csr[pos] = (unsigned short)ei[e];
    }
  }
}

__global__ void scan_block_sums(const int* __restrict__ deg, int* __restrict__ bsum, int n) {
  int tid = threadIdx.x;
  int i = blockIdx.x * 256 + tid;
  int v = (i < n) ? deg[i] : 0;
  for (int off = 32; off; off >>= 1) v += __shfl_down(v, off);
  __shared__ int ws[4];
  int lane = tid & 63, wid = tid >> 6;
  if (lane == 0) ws[wid] = v;
  __syncthreads();
  if (tid == 0) bsum[blockIdx.x] = ws[0] + ws[1] + ws[2] + ws[3];
}

// exclusive scan + cursor + dinv_g + dinv_c + rinv_c (= sqrt(deg), 0 if deg==0)
__global__ void scan_final(const int* __restrict__ deg, const int* __restrict__ bsum, int nb,
                           int* __restrict__ rowptr, int* __restrict__ cursor,
                           float* __restrict__ dg, float* __restrict__ dc,
                           float* __restrict__ rc, int n) {
  __shared__ int tmp[256];
  __shared__ int ws[4];
  __shared__ int base_sh;
  int tid = threadIdx.x;
  int v0 = (tid < nb && tid < (int)blockIdx.x) ? bsum[tid] : 0;
  for (int off = 32; off; off >>= 1) v0 += __shfl_down(v0, off);
  if ((tid & 63) == 0) ws[tid >> 6] = v0;
  __syncthreads();
  if (tid == 0) base_sh = ws[0] + ws[1] + ws[2] + ws[3];
  int i = blockIdx.x * 256 + tid;
  int v = (i < n) ? deg[i] : 0;
  tmp[tid] = v;
  __syncthreads();
  for (int off = 1; off < 256; off <<= 1) {
    int t = (tid >= off) ? tmp[tid - off] : 0;
    __syncthreads();
    tmp[tid] += t;
    __syncthreads();
  }
  if (i < n) {
    int excl = tmp[tid] - v + base_sh;
    rowptr[i] = excl;
    cursor[i] = excl;
    dg[i] = rsqrtf((float)v + 2.f);
    dc[i] = (v > 0) ? rsqrtf((float)v) : 0.f;
    rc[i] = (v > 0) ? sqrtf((float)v) : 0.f;
  }
}

// ---------- cast+scale x (N x 16 fp32) -> fp16 scaled by dinv_g ----------
__global__ void cast_x16_kernel(const float* __restrict__ x, const float* __restrict__ dg,
                                _Float16* __restrict__ x16s, int total) {
  int i = blockIdx.x * blockDim.x + threadIdx.x;
  if (i < total) x16s[i] = (_Float16)(dg[i >> 4] * x[i]);
}

// ---------- pack gate weights (folded) + w_gcn2 -> fp16 MFMA B-frag layout ----------
// Gate: tau0 -> W0-W2, tau1 -> W1, tau2 -> 2*W2.  idx >= 110592 -> w_gcn2 path.
__global__ void pack_all_kernel(const float* __restrict__ wx0, const float* __restrict__ wx1,
                                const float* __restrict__ wx2, const float* __restrict__ Wg2,
                                _Float16* __restrict__ Wpk, _Float16* __restrict__ Wpk2) {
  int idx = blockIdx.x * 256 + threadIdx.x;
  if (idx < 3 * 3 * 192 * 64) {
    int l = idx / 36864;
    int r = idx % 36864;
    int g = r / 12288;
    int r2 = r % 12288;
    int k = r2 / 64;
    int n = r2 % 64;
    const float* wx = (l == 0) ? wx0 : (l == 1 ? wx1 : wx2);
    int gs = (g == 0) ? 0 : (g == 1 ? 2 : 3);
    int tau = k >> 6, kd = k & 63;
    size_t base = ((size_t)gs * 3) * 4096 + (size_t)kd * 64 + n;
    float v;
    if (tau == 0)      v = wx[base] - wx[base + 2 * 4096];
    else if (tau == 1) v = wx[base + 1 * 4096];
    else               v = 2.f * wx[base + 2 * 4096];
    int kc = k >> 5, klo = k & 31;
    int lane = ((klo >> 3) << 4) | (n & 15);
    int j = klo & 7;
    int nt = n >> 4;
    Wpk[((((size_t)l * 3 + g) * 6 + kc) * 4 + nt) * 512 + (size_t)lane * 8 + j] = (_Float16)v;
  } else if (idx < 3 * 3 * 192 * 64 + 4096) {
    int i2 = idx - 110592;
    int k = i2 >> 6, n = i2 & 63;
    float v = Wg2[k * 64 + n];
    int kc = k >> 5, klo = k & 31;
    int lane = ((klo >> 3) << 4) | (n & 15);
    int j = klo & 7;
    int nt = n >> 4;
    Wpk2[(((size_t)kc * 4 + nt) * 64 + lane) * 8 + j] = (_Float16)v;
  }
}

// ---------- GCN1 fused: agg16 (parallel 32-lane gather) + 16->64 matmul ----------
__global__ __launch_bounds__(256) void gcn1_fused_kernel(
    const _Float16* __restrict__ X16s, const float* __restrict__ W1,
    const float* __restrict__ b1, const float* __restrict__ dg,
    _Float16* __restrict__ OUTs,
    const int* __restrict__ rowptr, const int* __restrict__ deg,
    const unsigned short* __restrict__ csr, int n) {
  __shared__ float w1s[16 * 64];
  int tid = threadIdx.x;
  for (int i = tid; i < 1024; i += 256) w1s[i] = W1[i];
  __syncthreads();
  int node = blockIdx.x * 8 + (tid >> 5);
  if (node >= n) return;
  int lane = tid & 63;
  int l32 = tid & 31;
  int eg = l32 >> 1, c8 = l32 & 1;
  int beg = rowptr[node], end = beg + deg[node];
  const half8* IN8 = (const half8*)X16s;
  float acc[8];
#pragma unroll
  for (int j = 0; j < 8; ++j) acc[j] = 0.f;
  for (int p = beg + eg; p < end; p += 16) {
    int s = csr[p];
    half8 v = IN8[(size_t)s * 2 + c8];
#pragma unroll
    for (int j = 0; j < 8; ++j) acc[j] += (float)v[j];
  }
#pragma unroll
  for (int j = 0; j < 8; ++j) {
    acc[j] += __shfl_xor(acc[j], 2);
    acc[j] += __shfl_xor(acc[j], 4);
    acc[j] += __shfl_xor(acc[j], 8);
    acc[j] += __shfl_xor(acc[j], 16);
  }
  float dt = dg[node];
  half8 self = IN8[(size_t)node * 2 + c8];
  float v8[8];
#pragma unroll
  for (int j = 0; j < 8; ++j) v8[j] = dt * acc[j] + 2.f * dt * (float)self[j];
  float agg[16];
  int base = lane & 32;
#pragma unroll
  for (int k = 0; k < 16; ++k) agg[k] = __shfl(v8[k & 7], base + (k >> 3));
  float h0 = b1[l32], h1 = b1[l32 + 32];
#pragma unroll
  for (int k = 0; k < 16; ++k) {
    h0 += agg[k] * w1s[k * 64 + l32];
    h1 += agg[k] * w1s[k * 64 + l32 + 32];
  }
  OUTs[(size_t)node * 64 + l32]      = (_Float16)(dt * fmaxf(h0, 0.f));
  OUTs[(size_t)node * 64 + l32 + 32] = (_Float16)(dt * fmaxf(h1, 0.f));
}

// ---------- gather (64-dim): wave/node, 8 slots x 8 half8-lanes, UNROLL x2 ----------
// MODE 0: GCN -> OUT = dt*acc + 2*dt*INs[node]
// MODE 1: z1s -> OUT = -dt*dt*acc
// MODE 3: y   -> OUT = -dt*acc
template <int MODE>
__global__ void gather_kernel(const int* __restrict__ rowptr, const int* __restrict__ deg,
                              const unsigned short* __restrict__ csr,
                              const float* __restrict__ dinv,
                              const _Float16* __restrict__ INs,
                              _Float16* __restrict__ OUT, int n) {
  int node = blockIdx.x * (blockDim.x >> 6) + (threadIdx.x >> 6);
  if (node >= n) return;
  int lane = threadIdx.x & 63;
  int eg = lane >> 3, c8 = lane & 7;
  int beg = rowptr[node], end = beg + deg[node];
  const half8* IN8 = (const half8*)INs;
  float acc[8], acc2[8];
#pragma unroll
  for (int j = 0; j < 8; ++j) { acc[j] = 0.f; acc2[j] = 0.f; }
  int p = beg + eg;
  for (; p + 8 < end; p += 16) {
    int s0 = csr[p];
    int s1 = csr[p + 8];
    half8 v0 = IN8[(size_t)s0 * 8 + c8];
    half8 v1 = IN8[(size_t)s1 * 8 + c8];
#pragma unroll
    for (int j = 0; j < 8; ++j) { acc[j] += (float)v0[j]; acc2[j] += (float)v1[j]; }
  }
  if (p < end) {
    int s = csr[p];
    half8 v = IN8[(size_t)s * 8 + c8];
#pragma unroll
    for (int j = 0; j < 8; ++j) acc[j] += (float)v[j];
  }
#pragma unroll
  for (int j = 0; j < 8; ++j) {
    acc[j] += acc2[j];
    acc[j] += __shfl_xor(acc[j], 8);
    acc[j] += __shfl_xor(acc[j], 16);
    acc[j] += __shfl_xor(acc[j], 32);
  }
  if (eg == 0) {
    float dt = dinv[node];
    size_t o8 = (size_t)node * 8 + c8;
    half8 r;
    if (MODE == 0) {
      half8 self = IN8[o8];
#pragma unroll
      for (int j = 0; j < 8; ++j) r[j] = (_Float16)(dt * acc[j] + 2.f * dt * (float)self[j]);
    } else if (MODE == 1) {
      float s = -dt * dt;
#pragma unroll
      for (int j = 0; j < 8; ++j) r[j] = (_Float16)(s * acc[j]);
    } else {
#pragma unroll
      for (int j = 0; j < 8; ++j) r[j] = (_Float16)(-dt * acc[j]);
    }
    ((half8*)OUT)[o8] = r;
  }
}

// ---------- GCN2 on MFMA: h2 = relu(A @ W2 + b); writes h2 and dc*h2 ----------
__global__ __launch_bounds__(256) void gcn2_mfma_kernel(
    const _Float16* __restrict__ A, const _Float16* __restrict__ W2,
    const float* __restrict__ bias, const float* __restrict__ dc,
    _Float16* __restrict__ OUT, _Float16* __restrict__ OUTs, int n) {
  int tid = threadIdx.x;
  int wid = tid >> 6, lane = tid & 63;
  int n0 = blockIdx.x * 64;
  int row = n0 + wid * 16 + (lane & 15);
  int rowc = min(row, n - 1);
  int ksub = (lane >> 4) << 3;
  int dbase = lane & 15;
  const _Float16* Wlane = W2 + (size_t)lane * 8;
  f32x4 acc[4];
#pragma unroll
  for (int nt = 0; nt < 4; ++nt) {
    float b = bias[nt * 16 + dbase];
    acc[nt] = (f32x4){b, b, b, b};
  }
#pragma unroll
  for (int kc = 0; kc < 2; ++kc) {
    half8 a = *(const half8*)&A[(size_t)rowc * 64 + (kc << 5) + ksub];
#pragma unroll
    for (int nt = 0; nt < 4; ++nt) {
      half8 b = *(const half8*)(Wlane + (size_t)(kc * 4 + nt) * 512);
      acc[nt] = __builtin_amdgcn_mfma_f32_16x16x32_f16(a, b, acc[nt], 0, 0, 0);
    }
  }
  int mrow = n0 + wid * 16 + ((lane >> 4) << 2);
#pragma unroll
  for (int nt = 0; nt < 4; ++nt) {
    int d = nt * 16 + dbase;
#pragma unroll
    for (int r = 0; r < 4; ++r) {
      int node = mrow + r;
      if (node < n) {
        float h = fmaxf(acc[nt][r], 0.f);
        OUT[(size_t)node * 64 + d] = (_Float16)h;
        OUTs[(size_t)node * 64 + d] = (_Float16)(dc[node] * h);
      }
    }
  }
}

// ---------- MFMA gate kernel: A-frags from X, Z1s*rinv, Y (folded weights) ----------
// FINAL=0: writes H and dc*H.  FINAL=1: fuses out = relu(H) @ lin_w + lin_b.
template <int FINAL>
__global__ __launch_bounds__(256) void gate_mfma_kernel(
    const _Float16* __restrict__ X, const _Float16* __restrict__ Z1s,
    const _Float16* __restrict__ Y,
    const _Float16* __restrict__ Wl,  // packed folded [3][6][4][64][8]
    const float* __restrict__ bx, const float* __restrict__ bh, const float* __restrict__ bg,
    const float* __restrict__ wc, const float* __restrict__ dc,
    const float* __restrict__ rinv,
    _Float16* __restrict__ H, _Float16* __restrict__ Hs,
    const float* __restrict__ lw, const float* __restrict__ lb,
    float* __restrict__ out, int n) {
  int tid = threadIdx.x;
  int wid = tid >> 6, lane = tid & 63;
  int n0 = blockIdx.x * 64;
  int row = n0 + wid * 16 + (lane & 15);
  int rowc = min(row, n - 1);
  int ksub = (lane >> 4) << 3;
  const _Float16* Wlane = Wl + (size_t)lane * 8;
  int dbase = lane & 15;
  float rv = rinv[rowc];   // sqrt(deg) — reconstructs z1 = z1s * rv

  f32x4 acc[3][4];
#pragma unroll
  for (int g = 0; g < 3; ++g) {
    int gs = (g == 0) ? 0 : (g == 1 ? 2 : 3);
#pragma unroll
    for (int nt = 0; nt < 4; ++nt) {
      int d = nt * 16 + dbase;
      float b = bx[gs * 64 + d] + bh[gs * 64 + d] + bg[gs * 64 + d];
      acc[g][nt] = (f32x4){b, b, b, b};
    }
  }
  const _Float16* T[3] = {X, Z1s, Y};
#pragma unroll
  for (int kc = 0; kc < 6; ++kc) {
    const _Float16* t = T[kc >> 1];
    half8 a = *(const half8*)&t[(size_t)rowc * 64 + ((kc & 1) << 5) + ksub];
    if (kc >= 2 && kc < 4) {
#pragma unroll
      for (int j = 0; j < 8; ++j) a[j] = (_Float16)((float)a[j] * rv);
    }
#pragma unroll
    for (int g = 0; g < 3; ++g) {
#pragma unroll
      for (int nt = 0; nt < 4; ++nt) {
        half8 b = *(const half8*)(Wlane + (size_t)((g * 6 + kc) * 4 + nt) * 512);
        acc[g][nt] = __builtin_amdgcn_mfma_f32_16x16x32_f16(a, b, acc[g][nt], 0, 0, 0);
      }
    }
  }
  int mrow = n0 + wid * 16 + ((lane >> 4) << 2);
  float po[4][3];
  if (FINAL) {
#pragma unroll
    for (int r = 0; r < 4; ++r) { po[r][0] = 0.f; po[r][1] = 0.f; po[r][2] = 0.f; }
  }
#pragma unroll
  for (int nt = 0; nt < 4; ++nt) {
    int d = nt * 16 + dbase;
    float wcd = wc[128 + d];
#pragma unroll
    for (int r = 0; r < 4; ++r) {
      float ig = 1.f / (1.f + expf(-acc[0][nt][r]));
      float tt = tanhf(acc[1][nt][r]);
      float Cn = ig * tt;
      float og = 1.f / (1.f + expf(-(acc[2][nt][r] + wcd * Cn)));
      float h = og * tanhf(Cn);
      if (FINAL) {
        float rl = fmaxf(h, 0.f);
        po[r][0] += rl * lw[d * 3 + 0];
        po[r][1] += rl * lw[d * 3 + 1];
        po[r][2] += rl * lw[d * 3 + 2];
      } else {
        int node = mrow + r;
        if (node < n) {
          H[(size_t)node * 64 + d] = (_Float16)h;
          Hs[(size_t)node * 64 + d] = (_Float16)(dc[node] * h);
        }
      }
    }
  }
  if (FINAL) {
#pragma unroll
    for (int m = 1; m < 16; m <<= 1) {
#pragma unroll
      for (int r = 0; r < 4; ++r) {
        po[r][0] += __shfl_xor(po[r][0], m);
        po[r][1] += __shfl_xor(po[r][1], m);
        po[r][2] += __shfl_xor(po[r][2], m);
      }
    }
    if (dbase == 0) {
#pragma unroll
      for (int r = 0; r < 4; ++r) {
        int node = mrow + r;
        if (node < n) {
          out[(size_t)node * 3 + 0] = po[r][0] + lb[0];
          out[(size_t)node * 3 + 1] = po[r][1] + lb[1];
          out[(size_t)node * 3 + 2] = po[r][2] + lb[2];
        }
      }
    }
  }
}

extern "C" void kernel_launch(void* const* d_in, const int* in_sizes, int n_in,
                              void* d_out, int out_size, void* d_ws, size_t ws_size,
                              hipStream_t stream) {
  const float* x      = (const float*)d_in[0];
  const int*   ei     = (const int*)d_in[1];
  const float* w_gcn1 = (const float*)d_in[2];
  const float* b_gcn1 = (const float*)d_in[3];
  const float* w_gcn2 = (const float*)d_in[4];
  const float* b_gcn2 = (const float*)d_in[5];
  const float* wx[3]  = {(const float*)d_in[6],  (const float*)d_in[12], (const float*)d_in[18]};
  const float* bx[3]  = {(const float*)d_in[7],  (const float*)d_in[13], (const float*)d_in[19]};
  const float* bh[3]  = {(const float*)d_in[9],  (const float*)d_in[15], (const float*)d_in[21]};
  const float* wc[3]  = {(const float*)d_in[10], (const float*)d_in[16], (const float*)d_in[22]};
  const float* bg[3]  = {(const float*)d_in[11], (const float*)d_in[17], (const float*)d_in[23]};
  const float* lin_w  = (const float*)d_in[24];
  const float* lin_b  = (const float*)d_in[25];
  float* out = (float*)d_out;

  int N = in_sizes[0] / 16;
  int E = in_sizes[1] / 2;
  int nsb = (N + 255) / 256;
  int chunk = (N + 7) / 8;

  char* ws = (char*)d_ws;
  size_t off = 0;
  auto alloc = [&](size_t bytes) {
    void* p = ws + off;
    off = (off + bytes + 255) & ~(size_t)255;
    return p;
  };
  int* deg        = (int*)alloc((size_t)N * 4);
  int* rowptr     = (int*)alloc((size_t)N * 4);
  int* cursor     = (int*)alloc((size_t)N * 4);
  int* bsum       = (int*)alloc((size_t)nsb * 4);
  unsigned short* csr = (unsigned short*)alloc((size_t)E * 2);
  float* dinv_g   = (float*)alloc((size_t)N * 4);
  float* dinv_c   = (float*)alloc((size_t)N * 4);
  float* rinv_c   = (float*)alloc((size_t)N * 4);
  _Float16* Wpk   = (_Float16*)alloc((size_t)3 * 36864 * 2);
  _Float16* Wpk2  = (_Float16*)alloc((size_t)4096 * 2);
  _Float16* x16s  = (_Float16*)alloc((size_t)N * 16 * 2);
  _Float16* bufA  = (_Float16*)alloc((size_t)N * 64 * 2);   // X (unscaled)
  _Float16* bufAs = (_Float16*)alloc((size_t)N * 64 * 2);   // dc*X
  _Float16* bufB  = (_Float16*)alloc((size_t)N * 64 * 2);   // h1s / z1s
  _Float16* bufC  = (_Float16*)alloc((size_t)N * 64 * 2);   // gcn2-agg / y
  (void)ws_size; (void)n_in; (void)out_size;

  hipMemsetAsync(deg, 0, (size_t)N * 4, stream);
  count_deg_x_kernel<<<4096, 256, 0, stream>>>(ei, deg, E, chunk);
  scan_block_sums<<<nsb, 256, 0, stream>>>(deg, bsum, N);
  scan_final<<<nsb, 256, 0, stream>>>(deg, bsum, nsb, rowptr, cursor,
                                      dinv_g, dinv_c, rinv_c, N);
  fill_x_kernel<<<4096, 256, 0, stream>>>(ei, cursor, csr, E, chunk);
  pack_all_kernel<<<(114688 + 255) / 256, 256, 0, stream>>>(wx[0], wx[1], wx[2], w_gcn2,
                                                            Wpk, Wpk2);
  cast_x16_kernel<<<(N * 16 + 255) / 256, 256, 0, stream>>>(x, dinv_g, x16s, N * 16);

  int nb64 = (N + 63) / 64;
  int nbw  = (N + 3) / 4;
  int nb8  = (N + 7) / 8;

  // GCN1 fused: h1s = dg*relu(agg16 @ W1 + b1)      -> bufB
  gcn1_fused_kernel<<<nb8, 256, 0, stream>>>(x16s, w_gcn1, b_gcn1, dinv_g, bufB,
                                             rowptr, deg, csr, N);
  // GCN2: aggC = agg(h1s); h2 = relu(aggC @ W2 + b2) -> bufA, bufAs
  gather_kernel<0><<<nbw, 256, 0, stream>>>(rowptr, deg, csr, dinv_g, bufB, bufC, N);
  gcn2_mfma_kernel<<<nb64, 256, 0, stream>>>(bufC, Wpk2, b_gcn2, dinv_c, bufA, bufAs, N);

  // 3x GCLSTM: z1s gather, y gather, gate (folded weights, z1 reconstructed)
  for (int l = 0; l < 3; ++l) {
    gather_kernel<1><<<nbw, 256, 0, stream>>>(rowptr, deg, csr, dinv_c, bufAs, bufB, N);
    gather_kernel<3><<<nbw, 256, 0, stream>>>(rowptr, deg, csr, dinv_c, bufB, bufC, N);
    if (l < 2) {
      gate_mfma_kernel<0><<<nb64, 256, 0, stream>>>(bufA, bufB, bufC, Wpk + (size_t)l * 36864,
                                                    bx[l], bh[l], bg[l], wc[l], dinv_c, rinv_c,
                                                    bufA, bufAs, nullptr, nullptr, nullptr, N);
    } else {
      gate_mfma_kernel<1><<<nb64, 256, 0, stream>>>(bufA, bufB, bufC, Wpk + (size_t)l * 36864,
                                                    bx[l], bh[l], bg[l], wc[l], dinv_c, rinv_c,
                                                    nullptr, nullptr, lin_w, lin_b, out, N);
    }
  }
}

// Round 11
// 345.261 us; speedup vs baseline: 1.5438x; 1.0364x over previous
//
#include <hip/hip_runtime.h>

// Social-STGCN forward: 2x GCN(improved) + 3x GCLSTM(K=3 Cheb, H=C=0) + linear.
// N=50000 nodes, E=800000 edges, D=64.
//
// Exact simplifications (H=C=0 per cell): gh(g)=bh[g]; f gate dead; Cn=i*t.
// z2 = 2*lhat(z1) - X  =>  gate = X@(W0-W2) + z1@W1 + y@(2*W2), y = lhat(z1).
// Gathers read PRE-SCALED tables; ALL edge indices preloaded in ONE coalesced
// csr[beg+lane] load (deg<=64 a.s.) and distributed via __shfl -> row loads
// issue back-to-back with no index-load latency in the chain (deg>64: fallback).
// z1 stored only as z1s = dc*z1; gate reconstructs z1 = z1s*sqrt(deg).
// CSR build XCD-range-partitioned. csr as ushort (N<65536). 17 dispatches.

typedef _Float16 half8 __attribute__((ext_vector_type(8)));
typedef float f32x4 __attribute__((ext_vector_type(4)));

// ---------- CSR build (XCD-range partitioned) ----------
__global__ void count_deg_x_kernel(const int* __restrict__ ei, int* __restrict__ deg,
                                   int E, int chunk) {
  int range = blockIdx.x & 7;
  int lo = range * chunk, hi = lo + chunk;
  int stride = (gridDim.x >> 3) * blockDim.x;
  for (int e = (blockIdx.x >> 3) * blockDim.x + threadIdx.x; e < E; e += stride) {
    int d = ei[E + e];
    if (d >= lo && d < hi) atomicAdd(&deg[d], 1);
  }
}

__global__ void fill_x_kernel(const int* __restrict__ ei, int* __restrict__ cursor,
                              unsigned short* __restrict__ csr, int E, int chunk) {
  int range = blockIdx.x & 7;
  int lo = range * chunk, hi = lo + chunk;
  int stride = (gridDim.x >> 3) * blockDim.x;
  for (int e = (blockIdx.x >> 3) * blockDim.x + threadIdx.x; e < E; e += stride) {
    int d = ei[E + e];
    if (d >= lo && d < hi) {
      int pos = atomicAdd(&cursor[d], 1);
      csr[pos] = (unsigned short)ei[e];
    }
  }
}

// ---------- prep: pack gate weights (folded) + w_gcn2 + zero deg ----------
__global__ void prep_kernel(const float* __restrict__ wx0, const float* __restrict__ wx1,
                            const float* __restrict__ wx2, const float* __restrict__ Wg2,
                            _Float16* __restrict__ Wpk, _Float16* __restrict__ Wpk2,
                            int* __restrict__ deg, int n) {
  int idx = blockIdx.x * 256 + threadIdx.x;
  if (idx < 110592) {
    int l = idx / 36864;
    int r = idx % 36864;
    int g = r / 12288;
    int r2 = r % 12288;
    int k = r2 / 64;
    int nn = r2 % 64;
    const float* wx = (l == 0) ? wx0 : (l == 1 ? wx1 : wx2);
    int gs = (g == 0) ? 0 : (g == 1 ? 2 : 3);
    int tau = k >> 6, kd = k & 63;
    size_t base = ((size_t)gs * 3) * 4096 + (size_t)kd * 64 + nn;
    float v;
    if (tau == 0)      v = wx[base] - wx[base + 2 * 4096];
    else if (tau == 1) v = wx[base + 1 * 4096];
    else               v = 2.f * wx[base + 2 * 4096];
    int kc = k >> 5, klo = k & 31;
    int lane = ((klo >> 3) << 4) | (nn & 15);
    int j = klo & 7;
    int nt = nn >> 4;
    Wpk[((((size_t)l * 3 + g) * 6 + kc) * 4 + nt) * 512 + (size_t)lane * 8 + j] = (_Float16)v;
  } else if (idx < 114688) {
    int i2 = idx - 110592;
    int k = i2 >> 6, nn = i2 & 63;
    float v = Wg2[k * 64 + nn];
    int kc = k >> 5, klo = k & 31;
    int lane = ((klo >> 3) << 4) | (nn & 15);
    int j = klo & 7;
    int nt = nn >> 4;
    Wpk2[(((size_t)kc * 4 + nt) * 64 + lane) * 8 + j] = (_Float16)v;
  } else if (idx < 114688 + n) {
    deg[idx - 114688] = 0;
  }
}

// ---------- block sums of deg  +  cast/scale x -> x16s (after count_deg) ----------
__global__ void sums_cast_kernel(const int* __restrict__ deg, int* __restrict__ bsum, int nsb,
                                 const float* __restrict__ x, _Float16* __restrict__ x16s,
                                 int n) {
  int tid = threadIdx.x;
  if ((int)blockIdx.x < nsb) {
    int i = blockIdx.x * 256 + tid;
    int v = (i < n) ? deg[i] : 0;
    for (int off = 32; off; off >>= 1) v += __shfl_down(v, off);
    __shared__ int ws[4];
    int lane = tid & 63, wid = tid >> 6;
    if (lane == 0) ws[wid] = v;
    __syncthreads();
    if (tid == 0) bsum[blockIdx.x] = ws[0] + ws[1] + ws[2] + ws[3];
  } else {
    int i = (blockIdx.x - nsb) * 256 + tid;
    if (i < n * 16) x16s[i] = (_Float16)(rsqrtf((float)deg[i >> 4] + 2.f) * x[i]);
  }
}

// exclusive scan + cursor + dinv_g + dinv_c + rinv_c (= sqrt(deg), 0 if deg==0)
__global__ void scan_final(const int* __restrict__ deg, const int* __restrict__ bsum, int nb,
                           int* __restrict__ rowptr, int* __restrict__ cursor,
                           float* __restrict__ dg, float* __restrict__ dc,
                           float* __restrict__ rc, int n) {
  __shared__ int tmp[256];
  __shared__ int ws[4];
  __shared__ int base_sh;
  int tid = threadIdx.x;
  int v0 = (tid < nb && tid < (int)blockIdx.x) ? bsum[tid] : 0;
  for (int off = 32; off; off >>= 1) v0 += __shfl_down(v0, off);
  if ((tid & 63) == 0) ws[tid >> 6] = v0;
  __syncthreads();
  if (tid == 0) base_sh = ws[0] + ws[1] + ws[2] + ws[3];
  int i = blockIdx.x * 256 + tid;
  int v = (i < n) ? deg[i] : 0;
  tmp[tid] = v;
  __syncthreads();
  for (int off = 1; off < 256; off <<= 1) {
    int t = (tid >= off) ? tmp[tid - off] : 0;
    __syncthreads();
    tmp[tid] += t;
    __syncthreads();
  }
  if (i < n) {
    int excl = tmp[tid] - v + base_sh;
    rowptr[i] = excl;
    cursor[i] = excl;
    dg[i] = rsqrtf((float)v + 2.f);
    dc[i] = (v > 0) ? rsqrtf((float)v) : 0.f;
    rc[i] = (v > 0) ? sqrtf((float)v) : 0.f;
  }
}

// ---------- GCN1 fused: agg16 (idx-preload gather) + 16->64 matmul ----------
__global__ __launch_bounds__(256) void gcn1_fused_kernel(
    const _Float16* __restrict__ X16s, const float* __restrict__ W1,
    const float* __restrict__ b1, const float* __restrict__ dg,
    _Float16* __restrict__ OUTs,
    const int* __restrict__ rowptr, const int* __restrict__ deg,
    const unsigned short* __restrict__ csr, int n) {
  __shared__ float w1s[16 * 64];
  int tid = threadIdx.x;
  for (int i = tid; i < 1024; i += 256) w1s[i] = W1[i];
  __syncthreads();
  int node = blockIdx.x * 8 + (tid >> 5);
  if (node >= n) return;
  int lane = tid & 63;
  int l32 = tid & 31;
  int eg = l32 >> 1, c8 = l32 & 1;
  int beg = rowptr[node], dgg = deg[node];
  const half8* IN8 = (const half8*)X16s;
  // preload up to 32 edge indices in one coalesced load (width-32 segment)
  int idx = 0;
  if (l32 < dgg) idx = csr[beg + l32];
  float acc[8];
#pragma unroll
  for (int j = 0; j < 8; ++j) acc[j] = 0.f;
  int kmaxU = (dgg + 15) >> 4; if (kmaxU > 2) kmaxU = 2;
  for (int k = 0; k < kmaxU; ++k) {
    int s = __shfl(idx, eg + 16 * k, 32);
    half8 v = IN8[(size_t)s * 2 + c8];
    if (eg + 16 * k < dgg) {
#pragma unroll
      for (int j = 0; j < 8; ++j) acc[j] += (float)v[j];
    }
  }
  for (int p = beg + eg + 32; p < beg + dgg; p += 16) {   // rare deg>32 tail
    int s = csr[p];
    half8 v = IN8[(size_t)s * 2 + c8];
#pragma unroll
    for (int j = 0; j < 8; ++j) acc[j] += (float)v[j];
  }
#pragma unroll
  for (int j = 0; j < 8; ++j) {
    acc[j] += __shfl_xor(acc[j], 2);
    acc[j] += __shfl_xor(acc[j], 4);
    acc[j] += __shfl_xor(acc[j], 8);
    acc[j] += __shfl_xor(acc[j], 16);
  }
  float dt = dg[node];
  half8 self = IN8[(size_t)node * 2 + c8];
  float v8[8];
#pragma unroll
  for (int j = 0; j < 8; ++j) v8[j] = dt * acc[j] + 2.f * dt * (float)self[j];
  float agg[16];
  int base = lane & 32;
#pragma unroll
  for (int k = 0; k < 16; ++k) agg[k] = __shfl(v8[k & 7], base + (k >> 3));
  float h0 = b1[l32], h1 = b1[l32 + 32];
#pragma unroll
  for (int k = 0; k < 16; ++k) {
    h0 += agg[k] * w1s[k * 64 + l32];
    h1 += agg[k] * w1s[k * 64 + l32 + 32];
  }
  OUTs[(size_t)node * 64 + l32]      = (_Float16)(dt * fmaxf(h0, 0.f));
  OUTs[(size_t)node * 64 + l32 + 32] = (_Float16)(dt * fmaxf(h1, 0.f));
}

// ---------- gather (64-dim): wave/node; idx-preload + shfl distribution ----------
// MODE 0: GCN -> OUT = dt*acc + 2*dt*INs[node]
// MODE 1: z1s -> OUT = -dt*dt*acc
// MODE 3: y   -> OUT = -dt*acc
template <int MODE>
__global__ void gather_kernel(const int* __restrict__ rowptr, const int* __restrict__ deg,
                              const unsigned short* __restrict__ csr,
                              const float* __restrict__ dinv,
                              const _Float16* __restrict__ INs,
                              _Float16* __restrict__ OUT, int n) {
  int node = blockIdx.x * (blockDim.x >> 6) + (threadIdx.x >> 6);
  if (node >= n) return;
  int lane = threadIdx.x & 63;
  int eg = lane >> 3, c8 = lane & 7;
  int beg = rowptr[node], dgg = deg[node];
  const half8* IN8 = (const half8*)INs;
  // preload up to 64 edge indices in ONE coalesced 128B load
  int idx = 0;
  if (lane < dgg) idx = csr[beg + lane];
  float acc[8], acc2[8];
#pragma unroll
  for (int j = 0; j < 8; ++j) { acc[j] = 0.f; acc2[j] = 0.f; }
  int kmaxU = (dgg + 7) >> 3; if (kmaxU > 8) kmaxU = 8;   // wave-uniform bound
  int k = 0;
  for (; k + 2 <= kmaxU; k += 2) {
    int s0 = __shfl(idx, eg + 8 * k);
    int s1 = __shfl(idx, eg + 8 * k + 8);
    half8 v0 = IN8[(size_t)s0 * 8 + c8];
    half8 v1 = IN8[(size_t)s1 * 8 + c8];
    if (eg + 8 * k < dgg) {
#pragma unroll
      for (int j = 0; j < 8; ++j) acc[j] += (float)v0[j];
    }
    if (eg + 8 * k + 8 < dgg) {
#pragma unroll
      for (int j = 0; j < 8; ++j) acc2[j] += (float)v1[j];
    }
  }
  if (k < kmaxU) {
    int s = __shfl(idx, eg + 8 * k);
    half8 v = IN8[(size_t)s * 8 + c8];
    if (eg + 8 * k < dgg) {
#pragma unroll
      for (int j = 0; j < 8; ++j) acc[j] += (float)v[j];
    }
  }
  for (int p = beg + eg + 64; p < beg + dgg; p += 8) {    // rare deg>64 tail
    int s = csr[p];
    half8 v = IN8[(size_t)s * 8 + c8];
#pragma unroll
    for (int j = 0; j < 8; ++j) acc[j] += (float)v[j];
  }
#pragma unroll
  for (int j = 0; j < 8; ++j) {
    acc[j] += acc2[j];
    acc[j] += __shfl_xor(acc[j], 8);
    acc[j] += __shfl_xor(acc[j], 16);
    acc[j] += __shfl_xor(acc[j], 32);
  }
  if (eg == 0) {
    float dt = dinv[node];
    size_t o8 = (size_t)node * 8 + c8;
    half8 r;
    if (MODE == 0) {
      half8 self = IN8[o8];
#pragma unroll
      for (int j = 0; j < 8; ++j) r[j] = (_Float16)(dt * acc[j] + 2.f * dt * (float)self[j]);
    } else if (MODE == 1) {
      float s = -dt * dt;
#pragma unroll
      for (int j = 0; j < 8; ++j) r[j] = (_Float16)(s * acc[j]);
    } else {
#pragma unroll
      for (int j = 0; j < 8; ++j) r[j] = (_Float16)(-dt * acc[j]);
    }
    ((half8*)OUT)[o8] = r;
  }
}

// ---------- GCN2 on MFMA: h2 = relu(A @ W2 + b); writes h2 and dc*h2 ----------
__global__ __launch_bounds__(256) void gcn2_mfma_kernel(
    const _Float16* __restrict__ A, const _Float16* __restrict__ W2,
    const float* __restrict__ bias, const float* __restrict__ dc,
    _Float16* __restrict__ OUT, _Float16* __restrict__ OUTs, int n) {
  int tid = threadIdx.x;
  int wid = tid >> 6, lane = tid & 63;
  int n0 = blockIdx.x * 64;
  int row = n0 + wid * 16 + (lane & 15);
  int rowc = min(row, n - 1);
  int ksub = (lane >> 4) << 3;
  int dbase = lane & 15;
  const _Float16* Wlane = W2 + (size_t)lane * 8;
  f32x4 acc[4];
#pragma unroll
  for (int nt = 0; nt < 4; ++nt) {
    float b = bias[nt * 16 + dbase];
    acc[nt] = (f32x4){b, b, b, b};
  }
#pragma unroll
  for (int kc = 0; kc < 2; ++kc) {
    half8 a = *(const half8*)&A[(size_t)rowc * 64 + (kc << 5) + ksub];
#pragma unroll
    for (int nt = 0; nt < 4; ++nt) {
      half8 b = *(const half8*)(Wlane + (size_t)(kc * 4 + nt) * 512);
      acc[nt] = __builtin_amdgcn_mfma_f32_16x16x32_f16(a, b, acc[nt], 0, 0, 0);
    }
  }
  int mrow = n0 + wid * 16 + ((lane >> 4) << 2);
#pragma unroll
  for (int nt = 0; nt < 4; ++nt) {
    int d = nt * 16 + dbase;
#pragma unroll
    for (int r = 0; r < 4; ++r) {
      int node = mrow + r;
      if (node < n) {
        float h = fmaxf(acc[nt][r], 0.f);
        OUT[(size_t)node * 64 + d] = (_Float16)h;
        OUTs[(size_t)node * 64 + d] = (_Float16)(dc[node] * h);
      }
    }
  }
}

// ---------- MFMA gate kernel: A-frags from X, Z1s*rinv, Y (folded weights) ----------
// FINAL=0: writes H and dc*H.  FINAL=1: fuses out = relu(H) @ lin_w + lin_b.
template <int FINAL>
__global__ __launch_bounds__(256) void gate_mfma_kernel(
    const _Float16* __restrict__ X, const _Float16* __restrict__ Z1s,
    const _Float16* __restrict__ Y,
    const _Float16* __restrict__ Wl,  // packed folded [3][6][4][64][8]
    const float* __restrict__ bx, const float* __restrict__ bh, const float* __restrict__ bg,
    const float* __restrict__ wc, const float* __restrict__ dc,
    const float* __restrict__ rinv,
    _Float16* __restrict__ H, _Float16* __restrict__ Hs,
    const float* __restrict__ lw, const float* __restrict__ lb,
    float* __restrict__ out, int n) {
  int tid = threadIdx.x;
  int wid = tid >> 6, lane = tid & 63;
  int n0 = blockIdx.x * 64;
  int row = n0 + wid * 16 + (lane & 15);
  int rowc = min(row, n - 1);
  int ksub = (lane >> 4) << 3;
  const _Float16* Wlane = Wl + (size_t)lane * 8;
  int dbase = lane & 15;
  float rv = rinv[rowc];   // sqrt(deg) — reconstructs z1 = z1s * rv

  f32x4 acc[3][4];
#pragma unroll
  for (int g = 0; g < 3; ++g) {
    int gs = (g == 0) ? 0 : (g == 1 ? 2 : 3);
#pragma unroll
    for (int nt = 0; nt < 4; ++nt) {
      int d = nt * 16 + dbase;
      float b = bx[gs * 64 + d] + bh[gs * 64 + d] + bg[gs * 64 + d];
      acc[g][nt] = (f32x4){b, b, b, b};
    }
  }
  const _Float16* T[3] = {X, Z1s, Y};
#pragma unroll
  for (int kc = 0; kc < 6; ++kc) {
    const _Float16* t = T[kc >> 1];
    half8 a = *(const half8*)&t[(size_t)rowc * 64 + ((kc & 1) << 5) + ksub];
    if (kc >= 2 && kc < 4) {
#pragma unroll
      for (int j = 0; j < 8; ++j) a[j] = (_Float16)((float)a[j] * rv);
    }
#pragma unroll
    for (int g = 0; g < 3; ++g) {
#pragma unroll
      for (int nt = 0; nt < 4; ++nt) {
        half8 b = *(const half8*)(Wlane + (size_t)((g * 6 + kc) * 4 + nt) * 512);
        acc[g][nt] = __builtin_amdgcn_mfma_f32_16x16x32_f16(a, b, acc[g][nt], 0, 0, 0);
      }
    }
  }
  int mrow = n0 + wid * 16 + ((lane >> 4) << 2);
  float po[4][3];
  if (FINAL) {
#pragma unroll
    for (int r = 0; r < 4; ++r) { po[r][0] = 0.f; po[r][1] = 0.f; po[r][2] = 0.f; }
  }
#pragma unroll
  for (int nt = 0; nt < 4; ++nt) {
    int d = nt * 16 + dbase;
    float wcd = wc[128 + d];
#pragma unroll
    for (int r = 0; r < 4; ++r) {
      float ig = 1.f / (1.f + expf(-acc[0][nt][r]));
      float tt = tanhf(acc[1][nt][r]);
      float Cn = ig * tt;
      float og = 1.f / (1.f + expf(-(acc[2][nt][r] + wcd * Cn)));
      float h = og * tanhf(Cn);
      if (FINAL) {
        float rl = fmaxf(h, 0.f);
        po[r][0] += rl * lw[d * 3 + 0];
        po[r][1] += rl * lw[d * 3 + 1];
        po[r][2] += rl * lw[d * 3 + 2];
      } else {
        int node = mrow + r;
        if (node < n) {
          H[(size_t)node * 64 + d] = (_Float16)h;
          Hs[(size_t)node * 64 + d] = (_Float16)(dc[node] * h);
        }
      }
    }
  }
  if (FINAL) {
#pragma unroll
    for (int m = 1; m < 16; m <<= 1) {
#pragma unroll
      for (int r = 0; r < 4; ++r) {
        po[r][0] += __shfl_xor(po[r][0], m);
        po[r][1] += __shfl_xor(po[r][1], m);
        po[r][2] += __shfl_xor(po[r][2], m);
      }
    }
    if (dbase == 0) {
#pragma unroll
      for (int r = 0; r < 4; ++r) {
        int node = mrow + r;
        if (node < n) {
          out[(size_t)node * 3 + 0] = po[r][0] + lb[0];
          out[(size_t)node * 3 + 1] = po[r][1] + lb[1];
          out[(size_t)node * 3 + 2] = po[r][2] + lb[2];
        }
      }
    }
  }
}

extern "C" void kernel_launch(void* const* d_in, const int* in_sizes, int n_in,
                              void* d_out, int out_size, void* d_ws, size_t ws_size,
                              hipStream_t stream) {
  const float* x      = (const float*)d_in[0];
  const int*   ei     = (const int*)d_in[1];
  const float* w_gcn1 = (const float*)d_in[2];
  const float* b_gcn1 = (const float*)d_in[3];
  const float* w_gcn2 = (const float*)d_in[4];
  const float* b_gcn2 = (const float*)d_in[5];
  const float* wx[3]  = {(const float*)d_in[6],  (const float*)d_in[12], (const float*)d_in[18]};
  const float* bx[3]  = {(const float*)d_in[7],  (const float*)d_in[13], (const float*)d_in[19]};
  const float* bh[3]  = {(const float*)d_in[9],  (const float*)d_in[15], (const float*)d_in[21]};
  const float* wc[3]  = {(const float*)d_in[10], (const float*)d_in[16], (const float*)d_in[22]};
  const float* bg[3]  = {(const float*)d_in[11], (const float*)d_in[17], (const float*)d_in[23]};
  const float* lin_w  = (const float*)d_in[24];
  const float* lin_b  = (const float*)d_in[25];
  float* out = (float*)d_out;

  int N = in_sizes[0] / 16;
  int E = in_sizes[1] / 2;
  int nsb = (N + 255) / 256;
  int chunk = (N + 7) / 8;

  char* ws = (char*)d_ws;
  size_t off = 0;
  auto alloc = [&](size_t bytes) {
    void* p = ws + off;
    off = (off + bytes + 255) & ~(size_t)255;
    return p;
  };
  int* deg        = (int*)alloc((size_t)N * 4);
  int* rowptr     = (int*)alloc((size_t)N * 4);
  int* cursor     = (int*)alloc((size_t)N * 4);
  int* bsum       = (int*)alloc((size_t)nsb * 4);
  unsigned short* csr = (unsigned short*)alloc((size_t)E * 2);
  float* dinv_g   = (float*)alloc((size_t)N * 4);
  float* dinv_c   = (float*)alloc((size_t)N * 4);
  float* rinv_c   = (float*)alloc((size_t)N * 4);
  _Float16* Wpk   = (_Float16*)alloc((size_t)3 * 36864 * 2);
  _Float16* Wpk2  = (_Float16*)alloc((size_t)4096 * 2);
  _Float16* x16s  = (_Float16*)alloc((size_t)N * 16 * 2);
  _Float16* bufA  = (_Float16*)alloc((size_t)N * 64 * 2);   // X (unscaled)
  _Float16* bufAs = (_Float16*)alloc((size_t)N * 64 * 2);   // dc*X
  _Float16* bufB  = (_Float16*)alloc((size_t)N * 64 * 2);   // h1s / z1s
  _Float16* bufC  = (_Float16*)alloc((size_t)N * 64 * 2);   // gcn2-agg / y
  (void)ws_size; (void)n_in; (void)out_size;

  // prep: pack all weights + zero deg (one dispatch)
  prep_kernel<<<(114688 + N + 255) / 256, 256, 0, stream>>>(wx[0], wx[1], wx[2], w_gcn2,
                                                            Wpk, Wpk2, deg, N);
  count_deg_x_kernel<<<4096, 256, 0, stream>>>(ei, deg, E, chunk);
  // block sums + x cast/scale (rsqrt(deg+2) inline) in one dispatch
  sums_cast_kernel<<<nsb + (N * 16 + 255) / 256, 256, 0, stream>>>(deg, bsum, nsb, x, x16s, N);
  scan_final<<<nsb, 256, 0, stream>>>(deg, bsum, nsb, rowptr, cursor,
                                      dinv_g, dinv_c, rinv_c, N);
  fill_x_kernel<<<4096, 256, 0, stream>>>(ei, cursor, csr, E, chunk);

  int nb64 = (N + 63) / 64;
  int nbw  = (N + 3) / 4;
  int nb8  = (N + 7) / 8;

  // GCN1 fused: h1s = dg*relu(agg16 @ W1 + b1)      -> bufB
  gcn1_fused_kernel<<<nb8, 256, 0, stream>>>(x16s, w_gcn1, b_gcn1, dinv_g, bufB,
                                             rowptr, deg, csr, N);
  // GCN2: aggC = agg(h1s); h2 = relu(aggC @ W2 + b2) -> bufA, bufAs
  gather_kernel<0><<<nbw, 256, 0, stream>>>(rowptr, deg, csr, dinv_g, bufB, bufC, N);
  gcn2_mfma_kernel<<<nb64, 256, 0, stream>>>(bufC, Wpk2, b_gcn2, dinv_c, bufA, bufAs, N);

  // 3x GCLSTM: z1s gather, y gather, gate (folded weights, z1 reconstructed)
  for (int l = 0; l < 3; ++l) {
    gather_kernel<1><<<nbw, 256, 0, stream>>>(rowptr, deg, csr, dinv_c, bufAs, bufB, N);
    gather_kernel<3><<<nbw, 256, 0, stream>>>(rowptr, deg, csr, dinv_c, bufB, bufC, N);
    if (l < 2) {
      gate_mfma_kernel<0><<<nb64, 256, 0, stream>>>(bufA, bufB, bufC, Wpk + (size_t)l * 36864,
                                                    bx[l], bh[l], bg[l], wc[l], dinv_c, rinv_c,
                                                    bufA, bufAs, nullptr, nullptr, nullptr, N);
    } else {
      gate_mfma_kernel<1><<<nb64, 256, 0, stream>>>(bufA, bufB, bufC, Wpk + (size_t)l * 36864,
                                                    bx[l], bh[l], bg[l], wc[l], dinv_c, rinv_c,
                                                    nullptr, nullptr, lin_w, lin_b, out, N);
    }
  }
}